// Round 17
// baseline (118.283 us; speedup 1.0000x reference)
//
#include <hip/hip_runtime.h>
#include <hip/hip_bf16.h>
#include <hip/hip_fp16.h>

// NAM_89739046683406: per-feature tiny MLP (B=32768, F=128, H=64)
// logit(b) = bias + sum_f [ relu(relu(x[b,f]*w1[f]+b1[f]) @ w2[f] + b2[f]) . w3[f] + b3[f] ]
// out = [1-sigmoid, sigmoid]
//
// R38 = R37 (fdot2 + setprio, best: 113.9us total / ~48.8us main) with
// 128-row chunks in the PROVEN BATCH shape: build all 8 bt fragments ->
// one prioritized MFMA+fdot2 cluster (8 independent bt streams) -> batch
// tail. R27 tested 128-chunks but confounded them with per-bt build->
// consume serialization (the thing batch structure beats); this isolates
// chunk size. Wins sought: loop iters 8->4 (chunk-edge costs halve) and
// 2x intra-cluster ILP to fill MFMA/fdot2 latency WITHIN the wave (no
// cross-chunk pipelining -- R35 showed the compiler mishandles that).
// Cost: hfrag 32->64 VGPR; est total ~115-130, under LB(256,3)'s ~170 cap
// (NOT R24's regime -- no min-waves coercion).
//
// Evidence ledger:
//   - WINS: R22 f16 pk-math (-15%); R33 fdot2 (-4%); R37 setprio (-3%).
//   - Occupancy CLOSED (R24/R26/R27/R34). ILP-pipelining CLOSED (R23/R35).
//   - x-path EXONERATED (R23/R25). Tail RETIRED (R28 neutral, R36 fail).
//   - MFMA-epilogue RETIRED (R30 NaN, R31 absmax 0.68).
//   - NO float-ext-vector arrays + __builtin_elementwise_* (R17/R18).
//   - Judge spills by FETCH/WRITE counters, not VGPR_Count.
// Failure signatures THIS round: FETCH/WRITE blowup = spill -> revert R37;
// neutral/worse with clean counters = chunk-size exonerated -> R37 stands
// as the session plateau.

#define B_SZ 32768
#define F_SZ 128
#define H_SZ 64

typedef _Float16 half8 __attribute__((ext_vector_type(8)));  // f16 x8 (4 VGPR)
typedef float floatx4 __attribute__((ext_vector_type(4)));   // fp32 x4 acc

union U8 { half8 v; unsigned u[4]; };

// pack two fp32 -> half2 bits (RNE)
__device__ __forceinline__ unsigned pkh(float lo, float hi) {
    __half2 h = __float22half2_rn(make_float2(lo, hi));
    return __builtin_bit_cast(unsigned, h);
}

// pack two fp32 -> half2 bits (RTZ, single v_cvt_pkrtz_f16_f32)
__device__ __forceinline__ unsigned cpk(float lo, float hi) {
    return __builtin_bit_cast(unsigned, __builtin_amdgcn_cvt_pkrtz(lo, hi));
}

// packed f16 relu via v_pk_max_f16
__device__ __forceinline__ unsigned relu2(unsigned a) {
    unsigned r;
    asm("v_pk_max_f16 %0, %1, %2" : "=v"(r) : "v"(a), "v"(0u));
    return r;
}

// f16-pair dot product with f32 accumulate: d = a.lo*b.lo + a.hi*b.hi + c
__device__ __forceinline__ float fdot2(unsigned a, unsigned b, float c) {
    float d;
    asm("v_dot2_f32_f16 %0, %1, %2, %3" : "=v"(d) : "v"(a), "v"(b), "v"(c));
    return d;
}

__device__ __forceinline__ __half2 bch2(unsigned u) {
    return __builtin_bit_cast(__half2, u);
}

// ---- main: block = 4 waves; wave wv owns feature f = (bx>>6)*4+wv,
//      rows [rg*512, rg*512+512), rg = bx&63. 4 chunks of 128 rows,
//      batch build -> prioritized MFMA+fdot2 cluster -> batch tail.
//      Output: part[gf][rb..rb+512) plain store (sole writer).
__global__ __launch_bounds__(256, 3)
void nam_main(const float* __restrict__ x,
              const float* __restrict__ w1, const float* __restrict__ b1,
              const float* __restrict__ b2, const float* __restrict__ w3,
              const float* __restrict__ b3,
              const float* __restrict__ w2,
              float* __restrict__ part)
{
    __shared__ float partial[4][512];    // 8KB

    const int tid  = threadIdx.x;
    const int lane = tid & 63;
    const int wv   = tid >> 6;           // 0..3
    const int l15  = lane & 15;
    const int quad = lane >> 4;
    const int rg   = blockIdx.x & 63;
    const int gf   = blockIdx.x >> 6;    // 0..31
    const int f    = gf * 4 + wv;
    const int rb   = rg * 512;

    // ---- per-wave resident tables ----
    // w2 A-fragments packed in-place from fp32 source (f16):
    // frag (gt,ks): elem j = w2[f][k=ks*32+quad*8+j][g=gt*16+l15]
    const float* w2f = w2 + (size_t)f * H_SZ * H_SZ;
    half8 wfrag[4][2];
    #pragma unroll
    for (int gt = 0; gt < 4; ++gt)
        #pragma unroll
        for (int ks = 0; ks < 2; ++ks) {
            const float* src = w2f + (ks * 32 + quad * 8) * H_SZ + gt * 16 + l15;
            U8 o;
            #pragma unroll
            for (int t = 0; t < 4; ++t)
                o.u[t] = pkh(src[(2 * t) * H_SZ], src[(2 * t + 1) * H_SZ]);
            wfrag[gt][ks] = o.v;
        }

    // w1/b1 as packed half2: element k = ks*32 + quad*8 + (2t, 2t+1)
    unsigned wk2[2][4], bk2[2][4];
    #pragma unroll
    for (int ks = 0; ks < 2; ++ks) {
        float wtmp[8], btmp[8];
        const float4* wq = (const float4*)(w1 + f * 64 + ks * 32 + quad * 8);
        const float4* bq = (const float4*)(b1 + f * 64 + ks * 32 + quad * 8);
        *(float4*)&wtmp[0] = wq[0]; *(float4*)&wtmp[4] = wq[1];
        *(float4*)&btmp[0] = bq[0]; *(float4*)&btmp[4] = bq[1];
        #pragma unroll
        for (int t = 0; t < 4; ++t) {
            wk2[ks][t] = pkh(wtmp[2 * t], wtmp[2 * t + 1]);
            bk2[ks][t] = pkh(btmp[2 * t], btmp[2 * t + 1]);
        }
    }

    // b2 as MFMA C operand quads; w3 as packed f16 pairs for fdot2:
    // pair p of tile gt covers g = gt*16 + quad*4 + {2p, 2p+1}
    floatx4 b2c[4];
    unsigned w3h[4][2];
    #pragma unroll
    for (int gt = 0; gt < 4; ++gt) {
        float4 bv  = *(const float4*)(b2 + f * 64 + gt * 16 + quad * 4);
        float4 wv3 = *(const float4*)(w3 + f * 64 + gt * 16 + quad * 4);
        b2c[gt] = floatx4{bv.x, bv.y, bv.z, bv.w};
        w3h[gt][0] = pkh(wv3.x, wv3.y);
        w3h[gt][1] = pkh(wv3.z, wv3.w);
    }
    const float b3f = b3[f];

    // ---- 4 chunks of 128 rows, software-pipelined x gather (2 loads/chunk)
    float xv0 = x[(size_t)(rb + lane) * F_SZ + f];
    float xv1 = x[(size_t)(rb + 64 + lane) * F_SZ + f];

    #pragma unroll 1
    for (int c = 0; c < 4; ++c) {
        float xn0, xn1;
        if (c < 3) {
            xn0 = x[(size_t)(rb + (c + 1) * 128 + lane) * F_SZ + f];
            xn1 = x[(size_t)(rb + (c + 1) * 128 + 64 + lane) * F_SZ + f];
        }

        // splat-pack both row halves, broadcast packed word per 16-row block
        unsigned xpk0 = __builtin_bit_cast(unsigned, __float2half2_rn(xv0));
        unsigned xpk1 = __builtin_bit_cast(unsigned, __float2half2_rn(xv1));
        unsigned xf[8];
        #pragma unroll
        for (int bt = 0; bt < 4; ++bt) {
            xf[bt]     = (unsigned)__shfl((int)xpk0, bt * 16 + l15, 64);
            xf[bt + 4] = (unsigned)__shfl((int)xpk1, bt * 16 + l15, 64);
        }

        // h1 B-fragments in packed f16: B[k=quad*8+j][n=bt*16+l15] (8 bt)
        half8 hfrag[8][2];
        #pragma unroll
        for (int ks = 0; ks < 2; ++ks)
            #pragma unroll
            for (int bt = 0; bt < 8; ++bt) {
                U8 o;
                #pragma unroll
                for (int t = 0; t < 4; ++t) {
                    __half2 h = __hfma2(bch2(xf[bt]), bch2(wk2[ks][t]), bch2(bk2[ks][t]));
                    o.u[t] = relu2(__builtin_bit_cast(unsigned, h));
                }
                hfrag[bt][ks] = o.v;
            }

        // prioritized MFMA+fdot2 cluster: 8 independent bt streams
        // D layout: g = gt*16 + quad*4 + i, n = bt*16 + l15
        float t[8] = {0.0f, 0.0f, 0.0f, 0.0f, 0.0f, 0.0f, 0.0f, 0.0f};
        __builtin_amdgcn_s_setprio(1);
        #pragma unroll
        for (int gt = 0; gt < 4; ++gt)
            #pragma unroll
            for (int bt = 0; bt < 8; ++bt) {
                floatx4 acc = __builtin_amdgcn_mfma_f32_16x16x32_f16(
                    wfrag[gt][0], hfrag[bt][0], b2c[gt], 0, 0, 0);
                acc = __builtin_amdgcn_mfma_f32_16x16x32_f16(
                    wfrag[gt][1], hfrag[bt][1], acc, 0, 0, 0);
                unsigned p0 = relu2(cpk(acc[0], acc[1]));
                unsigned p1 = relu2(cpk(acc[2], acc[3]));
                t[bt] = fdot2(p0, w3h[gt][0], t[bt]);
                t[bt] = fdot2(p1, w3h[gt][1], t[bt]);
            }
        __builtin_amdgcn_s_setprio(0);

        // quad-reduce (row = c*128 + bt*16 + l15), publish per-chunk rows
        #pragma unroll
        for (int bt = 0; bt < 8; ++bt) {
            t[bt] += __shfl_xor(t[bt], 16, 64);
            t[bt] += __shfl_xor(t[bt], 32, 64);
        }
        if (quad == 0) {
            #pragma unroll
            for (int bt = 0; bt < 8; ++bt)
                partial[wv][c * 128 + bt * 16 + l15] = t[bt] + b3f;
        }

        xv0 = xn0; xv1 = xn1;
    }

    __syncthreads();

    // block reduce over the 4 features -> plain coalesced store (sole writer)
    #pragma unroll
    for (int k = 0; k < 2; ++k) {
        int row = k * 256 + tid;
        float p = partial[0][row] + partial[1][row]
                + partial[2][row] + partial[3][row];
        part[(size_t)gf * B_SZ + rb + row] = p;
    }
}

// ---- final: 1 row/thread, sum 32 gf-partials + bias + sigmoid ----
__global__ __launch_bounds__(256)
void nam_final(const float* __restrict__ part, const float* __restrict__ bias,
               float* __restrict__ out)
{
    int b = blockIdx.x * 256 + threadIdx.x;
    float s = bias[0];
    #pragma unroll
    for (int gf = 0; gf < 32; ++gf)
        s += part[(size_t)gf * B_SZ + b];
    float p = 1.0f / (1.0f + __expf(-s));
    ((float2*)out)[b] = make_float2(1.0f - p, p);
}

extern "C" void kernel_launch(void* const* d_in, const int* in_sizes, int n_in,
                              void* d_out, int out_size, void* d_ws, size_t ws_size,
                              hipStream_t stream)
{
    const float* x    = (const float*)d_in[0];
    const float* w1   = (const float*)d_in[1];
    const float* b1   = (const float*)d_in[2];
    const float* w2   = (const float*)d_in[3];
    const float* b2   = (const float*)d_in[4];
    const float* w3   = (const float*)d_in[5];
    const float* b3   = (const float*)d_in[6];
    const float* bias = (const float*)d_in[7];
    float* out = (float*)d_out;

    float* part = (float*)d_ws;   // part[32][B_SZ], 4MB

    nam_main<<<dim3(2048), dim3(256), 0, stream>>>(
        x, w1, b1, b2, w3, b3, w2, part);
    nam_final<<<dim3(B_SZ / 256), dim3(256), 0, stream>>>(part, bias, out);
}

// Round 18
// 115.926 us; speedup vs baseline: 1.0203x; 1.0203x over previous
//
#include <hip/hip_runtime.h>
#include <hip/hip_bf16.h>
#include <hip/hip_fp16.h>

// NAM_89739046683406: per-feature tiny MLP (B=32768, F=128, H=64)
// logit(b) = bias + sum_f [ relu(relu(x[b,f]*w1[f]+b1[f]) @ w2[f] + b2[f]) . w3[f] + b3[f] ]
// out = [1-sigmoid, sigmoid]
//
// R39 = R37 (fdot2 + setprio, best: 113.9us total / 48.8us main) with the
// per-bt fdot2 chain split into two independent accumulators (ta = p0
// terms, tb = p1 terms, summed pre-reduce): dep chain 8 -> 4, +1 add/bt,
// +4 VGPR, pure f32 reassociation (zero numerics risk). Last untried
// serial-chain lever inside the proven body.
//
// Evidence ledger (18 rounds):
//   - WINS: R22 f16 pk-math (-15%); R33 fdot2 (-4%); R37 setprio (-3%).
//   - Occupancy CLOSED (R24 spills / R26,R34 under-reside / R27 loses).
//   - ILP-pipelining CLOSED (R23, R35 both regress; compiler re-serializes).
//   - Chunk-size CLOSED (R27 confounded, R38 clean: 128-row loses -- soft
//     spill: WRITE 4->5.85MB at flat VGPR).
//   - x-path EXONERATED (R23, R25). Tail RETIRED (R28 neutral, R36 fail).
//   - MFMA-epilogue RETIRED (R30 NaN, R31 absmax 0.68).
//   - NO float-ext-vector arrays + __builtin_elementwise_* (R17/R18).
//   - Judge spills by FETCH/WRITE counters, not VGPR_Count.
// If this round is neutral: every structural class and serial sub-chain is
// probed; R37-family is the session plateau (latency-bound, NOT roofline:
// HBM 5.5%, MfmaUtil 29%).

#define B_SZ 32768
#define F_SZ 128
#define H_SZ 64

typedef _Float16 half8 __attribute__((ext_vector_type(8)));  // f16 x8 (4 VGPR)
typedef float floatx4 __attribute__((ext_vector_type(4)));   // fp32 x4 acc

union U8 { half8 v; unsigned u[4]; };

// pack two fp32 -> half2 bits (RNE)
__device__ __forceinline__ unsigned pkh(float lo, float hi) {
    __half2 h = __float22half2_rn(make_float2(lo, hi));
    return __builtin_bit_cast(unsigned, h);
}

// pack two fp32 -> half2 bits (RTZ, single v_cvt_pkrtz_f16_f32)
__device__ __forceinline__ unsigned cpk(float lo, float hi) {
    return __builtin_bit_cast(unsigned, __builtin_amdgcn_cvt_pkrtz(lo, hi));
}

// packed f16 relu via v_pk_max_f16
__device__ __forceinline__ unsigned relu2(unsigned a) {
    unsigned r;
    asm("v_pk_max_f16 %0, %1, %2" : "=v"(r) : "v"(a), "v"(0u));
    return r;
}

// f16-pair dot product with f32 accumulate: d = a.lo*b.lo + a.hi*b.hi + c
__device__ __forceinline__ float fdot2(unsigned a, unsigned b, float c) {
    float d;
    asm("v_dot2_f32_f16 %0, %1, %2, %3" : "=v"(d) : "v"(a), "v"(b), "v"(c));
    return d;
}

__device__ __forceinline__ __half2 bch2(unsigned u) {
    return __builtin_bit_cast(__half2, u);
}

// ---- main: block = 4 waves; wave wv owns feature f = (bx>>6)*4+wv,
//      rows [rg*512, rg*512+512), rg = bx&63. 8 chunks of 64 rows.
//      Preamble packs w2[f] -> f16 A-fragments in registers.
//      Output: part[gf][rb..rb+512) plain store (sole writer).
__global__ __launch_bounds__(256, 3)
void nam_main(const float* __restrict__ x,
              const float* __restrict__ w1, const float* __restrict__ b1,
              const float* __restrict__ b2, const float* __restrict__ w3,
              const float* __restrict__ b3,
              const float* __restrict__ w2,
              float* __restrict__ part)
{
    __shared__ float partial[4][512];    // 8KB

    const int tid  = threadIdx.x;
    const int lane = tid & 63;
    const int wv   = tid >> 6;           // 0..3
    const int l15  = lane & 15;
    const int quad = lane >> 4;
    const int rg   = blockIdx.x & 63;
    const int gf   = blockIdx.x >> 6;    // 0..31
    const int f    = gf * 4 + wv;
    const int rb   = rg * 512;

    // ---- per-wave resident tables ----
    // w2 A-fragments packed in-place from fp32 source (f16):
    // frag (gt,ks): elem j = w2[f][k=ks*32+quad*8+j][g=gt*16+l15]
    const float* w2f = w2 + (size_t)f * H_SZ * H_SZ;
    half8 wfrag[4][2];
    #pragma unroll
    for (int gt = 0; gt < 4; ++gt)
        #pragma unroll
        for (int ks = 0; ks < 2; ++ks) {
            const float* src = w2f + (ks * 32 + quad * 8) * H_SZ + gt * 16 + l15;
            U8 o;
            #pragma unroll
            for (int t = 0; t < 4; ++t)
                o.u[t] = pkh(src[(2 * t) * H_SZ], src[(2 * t + 1) * H_SZ]);
            wfrag[gt][ks] = o.v;
        }

    // w1/b1 as packed half2: element k = ks*32 + quad*8 + (2t, 2t+1)
    unsigned wk2[2][4], bk2[2][4];
    #pragma unroll
    for (int ks = 0; ks < 2; ++ks) {
        float wtmp[8], btmp[8];
        const float4* wq = (const float4*)(w1 + f * 64 + ks * 32 + quad * 8);
        const float4* bq = (const float4*)(b1 + f * 64 + ks * 32 + quad * 8);
        *(float4*)&wtmp[0] = wq[0]; *(float4*)&wtmp[4] = wq[1];
        *(float4*)&btmp[0] = bq[0]; *(float4*)&btmp[4] = bq[1];
        #pragma unroll
        for (int t = 0; t < 4; ++t) {
            wk2[ks][t] = pkh(wtmp[2 * t], wtmp[2 * t + 1]);
            bk2[ks][t] = pkh(btmp[2 * t], btmp[2 * t + 1]);
        }
    }

    // b2 as MFMA C operand quads; w3 as packed f16 pairs for fdot2:
    // pair p of tile gt covers g = gt*16 + quad*4 + {2p, 2p+1}
    floatx4 b2c[4];
    unsigned w3h[4][2];
    #pragma unroll
    for (int gt = 0; gt < 4; ++gt) {
        float4 bv  = *(const float4*)(b2 + f * 64 + gt * 16 + quad * 4);
        float4 wv3 = *(const float4*)(w3 + f * 64 + gt * 16 + quad * 4);
        b2c[gt] = floatx4{bv.x, bv.y, bv.z, bv.w};
        w3h[gt][0] = pkh(wv3.x, wv3.y);
        w3h[gt][1] = pkh(wv3.z, wv3.w);
    }
    const float b3f = b3[f];

    // ---- 8 chunks of 64 rows, software-pipelined x gather ----
    float xv = x[(size_t)(rb + lane) * F_SZ + f];   // chunk 0

    #pragma unroll 1
    for (int c = 0; c < 8; ++c) {
        float xvn;
        if (c < 7)
            xvn = x[(size_t)(rb + (c + 1) * 64 + lane) * F_SZ + f];

        // splat-pack x to half2 once, broadcast packed word per 16-row block
        unsigned xpk = __builtin_bit_cast(unsigned, __float2half2_rn(xv));
        unsigned xf[4];
        #pragma unroll
        for (int bt = 0; bt < 4; ++bt)
            xf[bt] = (unsigned)__shfl((int)xpk, bt * 16 + l15, 64);

        // h1 B-fragments in packed f16: B[k=quad*8+j][n=bt*16+l15]
        half8 hfrag[4][2];
        #pragma unroll
        for (int ks = 0; ks < 2; ++ks)
            #pragma unroll
            for (int bt = 0; bt < 4; ++bt) {
                U8 o;
                #pragma unroll
                for (int t = 0; t < 4; ++t) {
                    __half2 h = __hfma2(bch2(xf[bt]), bch2(wk2[ks][t]), bch2(bk2[ks][t]));
                    o.u[t] = relu2(__builtin_bit_cast(unsigned, h));
                }
                hfrag[bt][ks] = o.v;
            }

        // MFMA f16 (C = b2c direct, D != C) + fdot2 epilogue, prioritized.
        // Dual accumulators per bt: ta (p0 terms), tb (p1 terms) -- dep
        // chain 8 -> 4 per stream. D layout: g = gt*16+quad*4+i, n = bt*16+l15
        float ta[4] = {0.0f, 0.0f, 0.0f, 0.0f};
        float tb[4] = {0.0f, 0.0f, 0.0f, 0.0f};
        __builtin_amdgcn_s_setprio(1);
        #pragma unroll
        for (int gt = 0; gt < 4; ++gt)
            #pragma unroll
            for (int bt = 0; bt < 4; ++bt) {
                floatx4 acc = __builtin_amdgcn_mfma_f32_16x16x32_f16(
                    wfrag[gt][0], hfrag[bt][0], b2c[gt], 0, 0, 0);
                acc = __builtin_amdgcn_mfma_f32_16x16x32_f16(
                    wfrag[gt][1], hfrag[bt][1], acc, 0, 0, 0);
                unsigned p0 = relu2(cpk(acc[0], acc[1]));
                unsigned p1 = relu2(cpk(acc[2], acc[3]));
                ta[bt] = fdot2(p0, w3h[gt][0], ta[bt]);
                tb[bt] = fdot2(p1, w3h[gt][1], tb[bt]);
            }
        __builtin_amdgcn_s_setprio(0);

        // quad-reduce (row = bt*16 + l15), publish per-chunk rows
        float t[4];
        #pragma unroll
        for (int bt = 0; bt < 4; ++bt) {
            t[bt] = ta[bt] + tb[bt];
            t[bt] += __shfl_xor(t[bt], 16, 64);
            t[bt] += __shfl_xor(t[bt], 32, 64);
        }
        if (quad == 0) {
            #pragma unroll
            for (int bt = 0; bt < 4; ++bt)
                partial[wv][c * 64 + bt * 16 + l15] = t[bt] + b3f;
        }

        xv = xvn;
    }

    __syncthreads();

    // block reduce over the 4 features -> plain coalesced store (sole writer)
    #pragma unroll
    for (int k = 0; k < 2; ++k) {
        int row = k * 256 + tid;
        float p = partial[0][row] + partial[1][row]
                + partial[2][row] + partial[3][row];
        part[(size_t)gf * B_SZ + rb + row] = p;
    }
}

// ---- final: 1 row/thread, sum 32 gf-partials + bias + sigmoid ----
__global__ __launch_bounds__(256)
void nam_final(const float* __restrict__ part, const float* __restrict__ bias,
               float* __restrict__ out)
{
    int b = blockIdx.x * 256 + threadIdx.x;
    float s = bias[0];
    #pragma unroll
    for (int gf = 0; gf < 32; ++gf)
        s += part[(size_t)gf * B_SZ + b];
    float p = 1.0f / (1.0f + __expf(-s));
    ((float2*)out)[b] = make_float2(1.0f - p, p);
}

extern "C" void kernel_launch(void* const* d_in, const int* in_sizes, int n_in,
                              void* d_out, int out_size, void* d_ws, size_t ws_size,
                              hipStream_t stream)
{
    const float* x    = (const float*)d_in[0];
    const float* w1   = (const float*)d_in[1];
    const float* b1   = (const float*)d_in[2];
    const float* w2   = (const float*)d_in[3];
    const float* b2   = (const float*)d_in[4];
    const float* w3   = (const float*)d_in[5];
    const float* b3   = (const float*)d_in[6];
    const float* bias = (const float*)d_in[7];
    float* out = (float*)d_out;

    float* part = (float*)d_ws;   // part[32][B_SZ], 4MB

    nam_main<<<dim3(2048), dim3(256), 0, stream>>>(
        x, w1, b1, b2, w3, b3, w2, part);
    nam_final<<<dim3(B_SZ / 256), dim3(256), 0, stream>>>(part, bias, out);
}